// Round 6
// baseline (107.839 us; speedup 1.0000x reference)
//
#include <hip/hip_runtime.h>

// Problem constants (fixed by reference)
constexpr int N_AG = 4096;   // N agents
constexpr int M_CL = 256;    // M clusters
constexpr int KD   = 32;     // K dim
constexpr float WEPS = 1e-6f;

// ws layout: only vT (32 x 4096) k-major remains.
constexpr int VT_OFF = 0;

typedef __attribute__((ext_vector_type(8))) short short8;   // 8 bf16 (4 VGPRs)
typedef __attribute__((ext_vector_type(4))) float f32x4;
typedef __attribute__((ext_vector_type(4))) unsigned uint4v;

__device__ __forceinline__ float rlane(float x, int l) {
    return __int_as_float(__builtin_amdgcn_readlane(__float_as_int(x), l));
}

__device__ __forceinline__ float fast_rcp(float x) {
#if __has_builtin(__builtin_amdgcn_rcpf)
    float r = __builtin_amdgcn_rcpf(x);      // v_rcp_f32 (~1 ulp)
    return r * (2.0f - x * r);               // +1 NR step -> ~2^-29 rel err
#else
    return 1.0f / x;
#endif
}

// ---------------------------------------------------------------------------
// Solve: row-layout forward elimination + back-substitution (R9).
// Lane r (r = lane&31; lanes 32-63 duplicate rows 0-31 so broadcasts stay
// readlane-uniform, zero divergence) holds row r of A + rhs scalar.
// No pivoting: SPD with diag >= 1. Template-recursive so all a[j] indices
// are compile-time (R6 scratch lesson).
// ---------------------------------------------------------------------------
template<int J>
struct FE {
    static __device__ __forceinline__ void run(float (&a)[32], float& rhs,
                                               float& pl, const int rr) {
        const float piv  = rlane(a[J], J);
        const float pinv = fast_rcp(piv);
        if (rr == J) pl = pinv;                       // save for back-sub
        const float f = (rr > J) ? a[J] * pinv : 0.0f; // rows <= J frozen
        #pragma unroll
        for (int j = J + 1; j < 32; ++j) {
            const float rJ = rlane(a[j], J);
            a[j] = fmaf(-f, rJ, a[j]);
        }
        const float rb = rlane(rhs, J);
        rhs = fmaf(-f, rb, rhs);
        FE<J + 1>::run(a, rhs, pl, rr);
    }
};
template<> struct FE<32> {
    static __device__ __forceinline__ void run(float (&)[32], float&, float&, const int) {}
};

template<int J>
struct BS {
    static __device__ __forceinline__ void run(const float (&a)[32], float& rhs,
                                               const float pl, float& xv, const int rr) {
        const float xj = rlane(rhs, J) * rlane(pl, J);  // uniform
        if (rr == J) xv = xj;
        rhs = fmaf(-a[J], xj, rhs);   // corrupts rr>=J lanes: already consumed
        BS<J - 1>::run(a, rhs, pl, xv, rr);
    }
};
template<> struct BS<-1> {
    static __device__ __forceinline__ void run(const float (&)[32], float&,
                                               const float, float&, const int) {}
};

// ---------------------------------------------------------------------------
// K1: pure solve, 1024 blocks. 4 matrices/block, 1 wave each, then in-block
// LDS transpose -> vT (32 x 4096) k-major.  (Unchanged from R5.)
// ---------------------------------------------------------------------------
__global__ __launch_bounds__(256) void solve_kernel(const float* __restrict__ mu,
                                                    const float* __restrict__ oc,
                                                    float* __restrict__ ws) {
    __shared__ float sv[4][32];
    const int t    = threadIdx.x;
    const int lane = t & 63;
    const int wid  = t >> 6;
    const int n0   = blockIdx.x * 4;
    const int idx  = n0 + wid;
    const int rr   = lane & 31;           // lanes 32-63 mirror rows 0-31

    float a[32];
    const float4* src = reinterpret_cast<const float4*>(oc + (size_t)idx * 1024 + rr * 32);
    #pragma unroll
    for (int q = 0; q < 8; ++q) {
        const float4 t4 = src[q];
        a[4 * q + 0] = t4.x; a[4 * q + 1] = t4.y;
        a[4 * q + 2] = t4.z; a[4 * q + 3] = t4.w;
    }
    float rhs = mu[(size_t)idx * 32 + rr];
    float pl = 0.0f, xv = 0.0f;

    FE<0>::run(a, rhs, pl, rr);
    BS<31>::run(a, rhs, pl, xv, rr);

    if (lane < 32) sv[wid][lane] = xv;
    __syncthreads();
    // vT[k][n0..n0+3]: 16B-coalesced per k-row
    if (t < 128) {
        const int k = t >> 2;
        const int j = t & 3;
        ws[VT_OFF + (size_t)k * 4096 + n0 + j] = sv[j][k];
    }
}

// ---------------------------------------------------------------------------
// Fragment builder (ROUND-12): 8 consecutive-n u-values -> bf16 hi/lo short8
// pair, entirely in registers. Truncation (RTZ via perm) identical to the
// old LDS-staged path -> bit-identical MFMA operands.
// Also accumulates S1 partial: s1 += sum_n sw_n * u_n  (= sum w*v).
// ---------------------------------------------------------------------------
__device__ __forceinline__ void mk_frag(const float4 v0, const float4 v1,
                                        const float4 s0, const float4 s1v,
                                        short8& hi, short8& lo, float& s1) {
    const float u0 = v0.x * s0.x,  u1 = v0.y * s0.y;
    const float u2 = v0.z * s0.z,  u3 = v0.w * s0.w;
    const float u4 = v1.x * s1v.x, u5 = v1.y * s1v.y;
    const float u6 = v1.z * s1v.z, u7 = v1.w * s1v.w;

    const unsigned b0 = __float_as_uint(u0), b1 = __float_as_uint(u1);
    const unsigned b2 = __float_as_uint(u2), b3 = __float_as_uint(u3);
    const unsigned b4 = __float_as_uint(u4), b5 = __float_as_uint(u5);
    const unsigned b6 = __float_as_uint(u6), b7 = __float_as_uint(u7);

    union { uint4v u; short8 s; } H, L;
    H.u[0] = __builtin_amdgcn_perm(b1, b0, 0x07060302u);
    H.u[1] = __builtin_amdgcn_perm(b3, b2, 0x07060302u);
    H.u[2] = __builtin_amdgcn_perm(b5, b4, 0x07060302u);
    H.u[3] = __builtin_amdgcn_perm(b7, b6, 0x07060302u);

    const float l0 = u0 - __uint_as_float(b0 & 0xFFFF0000u);
    const float l1 = u1 - __uint_as_float(b1 & 0xFFFF0000u);
    const float l2 = u2 - __uint_as_float(b2 & 0xFFFF0000u);
    const float l3 = u3 - __uint_as_float(b3 & 0xFFFF0000u);
    const float l4 = u4 - __uint_as_float(b4 & 0xFFFF0000u);
    const float l5 = u5 - __uint_as_float(b5 & 0xFFFF0000u);
    const float l6 = u6 - __uint_as_float(b6 & 0xFFFF0000u);
    const float l7 = u7 - __uint_as_float(b7 & 0xFFFF0000u);
    L.u[0] = __builtin_amdgcn_perm(__float_as_uint(l1), __float_as_uint(l0), 0x07060302u);
    L.u[1] = __builtin_amdgcn_perm(__float_as_uint(l3), __float_as_uint(l2), 0x07060302u);
    L.u[2] = __builtin_amdgcn_perm(__float_as_uint(l5), __float_as_uint(l4), 0x07060302u);
    L.u[3] = __builtin_amdgcn_perm(__float_as_uint(l7), __float_as_uint(l6), 0x07060302u);

    s1 = fmaf(s0.x, u0, s1);  s1 = fmaf(s0.y, u1, s1);
    s1 = fmaf(s0.z, u2, s1);  s1 = fmaf(s0.w, u3, s1);
    s1 = fmaf(s1v.x, u4, s1); s1 = fmaf(s1v.y, u5, s1);
    s1 = fmaf(s1v.z, u6, s1); s1 = fmaf(s1v.w, u7, s1);

    hi = H.s; lo = L.s;
}

// ---------------------------------------------------------------------------
// K2 (ROUND-12): direct-fragment mega-fusion. One block per m (256 x 1024).
// CHANGE vs R5: the main loop's LDS staging round-trip (ds_write -> same-wave
// lgkm wait -> ds_read_b128 -> MFMA) is deleted. Each lane loads its MFMA
// fragment slice DIRECTLY from vT — u[n0+g*8 .. +8, a] is 8 consecutive n at
// fixed k-row a, i.e. 2 float4s of vT row a — scales by sw (LDS broadcast,
// shared by the 16 lanes with equal g), and builds the bf16 hi/lo fragments
// in registers (mk_frag). Register contents bit-identical to the staged path
// -> identical MFMA results. Zero barriers and zero LDS writes in the main
// loop: the compiler can pipeline vT loads across rounds freely.
// S1 becomes two per-lane register accumulators (rows a, a+16), reduced by
// 2 shfl_xor at the end (replaces per-round shuffle + atomicAdd).
// LDS: pred[16][1024] (P cross-wave reduce, epilogue only) 64 KB
//    + swbuf 16 KB = 80 KB -> 1 block/CU, 4 waves/SIMD (same occupancy).
// Math identical: u = sqrt(w)v hi/lo split, S2 = u^T u via MFMA,
// P = hh + 2*hl (G symmetric => tr(G(hl+hl^T)) = 2 tr(G hl)).
// Epilogue bijection unchanged: thread t holds element t of P,
//   q=t>>8, r=(t>>6)&3, a=(q>>1)*16+((t>>4)&3)*4+r, b=(q&1)*16+(t&15).
// ---------------------------------------------------------------------------
__global__ __launch_bounds__(1024, 4) void fused_kernel(const float* __restrict__ W,
                                                        const float* __restrict__ vT,
                                                        const float* __restrict__ op,
                                                        float* __restrict__ out) {
    const int m  = blockIdx.x;
    const int t  = threadIdx.x;
    const int lane = t & 63;
    const int wv   = t >> 6;     // wave id 0..15

    __shared__ float pred[16][1024];   // P cross-wave reduce: 65,536 B
    __shared__ float swbuf[4096];      // sqrt(w); dead after main loop: 16,384 B
    // post-loop overlays inside swbuf:
    float* const s1buf = swbuf;            // [0..31]
    float* const zredL = swbuf + 32;       // [32..47]
    float* const credL = swbuf + 48;       // [48..63]
    float* const omg   = swbuf + 64;       // [64..1119]  32*33
    float* const vbar  = swbuf + 1120;     // [1120..1151]
    float* const red2  = swbuf + 1152;     // [1152..1167]

    // ---- stage w: direct strided W read (column m), mask, sqrt, Z, count ----
    // thread t covers rows 4t..4t+3; wave wv's main loop reads swbuf slice
    // [wv*256, +256) written by its own threads -> wave-private, no barrier.
    const int rbase = t * 4;
    const float w0 = W[(size_t)(rbase + 0) * 256 + m];
    const float w1 = W[(size_t)(rbase + 1) * 256 + m];
    const float w2 = W[(size_t)(rbase + 2) * 256 + m];
    const float w3 = W[(size_t)(rbase + 3) * 256 + m];
    const float m0 = (w0 >= WEPS) ? w0 : 0.0f;
    const float m1 = (w1 >= WEPS) ? w1 : 0.0f;
    const float m2 = (w2 >= WEPS) ? w2 : 0.0f;
    const float m3 = (w3 >= WEPS) ? w3 : 0.0f;
    float zacc = m0 + m1 + m2 + m3;
    float cacc = (w0 >= WEPS ? 1.f : 0.f) + (w1 >= WEPS ? 1.f : 0.f)
               + (w2 >= WEPS ? 1.f : 0.f) + (w3 >= WEPS ? 1.f : 0.f);
    reinterpret_cast<float4*>(swbuf)[t] =
        make_float4(sqrtf(m0), sqrtf(m1), sqrtf(m2), sqrtf(m3));

    f32x4 Chh[4], Chl[4];
    #pragma unroll
    for (int q = 0; q < 4; ++q) {
        Chh[q] = (f32x4){0.f, 0.f, 0.f, 0.f};
        Chl[q] = (f32x4){0.f, 0.f, 0.f, 0.f};
    }

    const int g = lane >> 4;          // 0..3 : n-subchunk within the 32-n round
    const int a = lane & 15;          // 0..15: k-row of fragment (h1 row = a+16)
    float s1A = 0.0f, s1B = 0.0f;     // S1 partials for rows a, a+16

    for (int rnd = 0; rnd < 8; ++rnd) {
        const int n0 = wv * 256 + rnd * 32 + g * 8;   // global n base of this lane's slice

        // sw slice (LDS broadcast: 16 lanes with equal g read the same 32 B)
        const float4 sw0 = *reinterpret_cast<const float4*>(&swbuf[n0]);
        const float4 sw1 = *reinterpret_cast<const float4*>(&swbuf[n0 + 4]);
        // vT fragment slices: rows a and a+16, 8 consecutive n each
        const float4 vA0 = *reinterpret_cast<const float4*>(vT + (size_t)a * 4096 + n0);
        const float4 vA1 = *reinterpret_cast<const float4*>(vT + (size_t)a * 4096 + n0 + 4);
        const float4 vB0 = *reinterpret_cast<const float4*>(vT + (size_t)(a + 16) * 4096 + n0);
        const float4 vB1 = *reinterpret_cast<const float4*>(vT + (size_t)(a + 16) * 4096 + n0 + 4);

        short8 h0, l0, h1, l1;
        mk_frag(vA0, vA1, sw0, sw1, h0, l0, s1A);
        mk_frag(vB0, vB1, sw0, sw1, h1, l1, s1B);

        Chh[0] = __builtin_amdgcn_mfma_f32_16x16x32_bf16(h0, h0, Chh[0], 0, 0, 0);
        Chh[1] = __builtin_amdgcn_mfma_f32_16x16x32_bf16(h0, h1, Chh[1], 0, 0, 0);
        Chh[2] = __builtin_amdgcn_mfma_f32_16x16x32_bf16(h1, h0, Chh[2], 0, 0, 0);
        Chh[3] = __builtin_amdgcn_mfma_f32_16x16x32_bf16(h1, h1, Chh[3], 0, 0, 0);
        Chl[0] = __builtin_amdgcn_mfma_f32_16x16x32_bf16(h0, l0, Chl[0], 0, 0, 0);
        Chl[1] = __builtin_amdgcn_mfma_f32_16x16x32_bf16(h0, l1, Chl[1], 0, 0, 0);
        Chl[2] = __builtin_amdgcn_mfma_f32_16x16x32_bf16(h1, l0, Chl[2], 0, 0, 0);
        Chl[3] = __builtin_amdgcn_mfma_f32_16x16x32_bf16(h1, l1, Chl[3], 0, 0, 0);
    }

    // ---- S1 reduce over the 4 g-lanes sharing each k-row ----
    s1A += __shfl_xor(s1A, 16); s1A += __shfl_xor(s1A, 32);
    s1B += __shfl_xor(s1B, 16); s1B += __shfl_xor(s1B, 32);

    // ---- P scatter: P = hh + 2*hl in MFMA-native lane layout (wave-private) ----
    #pragma unroll
    for (int q = 0; q < 4; ++q) {
        #pragma unroll
        for (int r = 0; r < 4; ++r) {
            pred[wv][q * 256 + r * 64 + lane] = Chh[q][r] + 2.0f * Chl[q][r];
        }
    }

    // ---- wave-level Z/count reduce (registers) ----
    #pragma unroll
    for (int s = 1; s < 64; s <<= 1) {
        zacc += __shfl_xor(zacc, s);
        cacc += __shfl_xor(cacc, s);
    }

    __syncthreads();   // B1: all scatters done; swbuf dead -> overlays live

    if (t < 32) s1buf[t] = 0.0f;
    if (lane == 0) { zredL[wv] = zacc; credL[wv] = cacc; }
    omg[(t >> 5) * 33 + (t & 31)] = op[(size_t)m * 1024 + t];

    // ---- cross-wave P sum: thread t accumulates element t over 16 waves ----
    float Ptot = 0.0f;
    #pragma unroll
    for (int ww = 0; ww < 16; ++ww) Ptot += pred[ww][t];

    __syncthreads();   // B2: s1buf zeroed, omg/zred/cred staged

    if (lane < 16) {
        atomicAdd(&s1buf[a], s1A);
        atomicAdd(&s1buf[a + 16], s1B);
    }
    __syncthreads();   // B3: s1 complete

    float Z = 0.0f, C = 0.0f;
    #pragma unroll
    for (int w = 0; w < 16; ++w) { Z += zredL[w]; C += credL[w]; }
    const float invZ = 1.0f / fmaxf(Z, 1e-30f);
    if (t < 32) vbar[t] = s1buf[t] * invZ;
    __syncthreads();   // B4: vbar ready

    // ---- per-thread combine: (a,b) from the P lane-layout bijection ----
    const int q2 = t >> 8;
    const int r2 = (t >> 6) & 3;
    const int pa = (q2 >> 1) * 16 + ((t >> 4) & 3) * 4 + r2;
    const int pb = (q2 & 1) * 16 + (t & 15);
    float G = 0.0f;
    #pragma unroll
    for (int i = 0; i < 32; ++i)
        G = fmaf(omg[i * 33 + pa], omg[i * 33 + pb], G);
    float val = G * (Ptot * invZ - vbar[pa] * vbar[pb]);

    #pragma unroll
    for (int s = 1; s < 64; s <<= 1) val += __shfl_xor(val, s);
    if (lane == 0) red2[wv] = val;
    __syncthreads();   // B5
    if (t == 0) {
        float acc = 0.0f;
        #pragma unroll
        for (int w = 0; w < 16; ++w) acc += red2[w];
        out[m] = (C >= 1.5f) ? acc : 0.0f;
    }
}

// ---------------------------------------------------------------------------
extern "C" void kernel_launch(void* const* d_in, const int* in_sizes, int n_in,
                              void* d_out, int out_size, void* d_ws, size_t ws_size,
                              hipStream_t stream) {
    const float* W  = (const float*)d_in[0];  // (4096, 256)
    const float* mu = (const float*)d_in[1];  // (4096, 32)
    const float* oc = (const float*)d_in[2];  // (4096, 32, 32)
    const float* op = (const float*)d_in[3];  // (256, 32, 32)
    float* out = (float*)d_out;               // (256,)
    float* ws  = (float*)d_ws;

    solve_kernel<<<1024, 256, 0, stream>>>(mu, oc, ws);
    fused_kernel<<<256, 1024, 0, stream>>>(W, ws + VT_OFF, op, out);
}

// Round 7
// 102.141 us; speedup vs baseline: 1.0558x; 1.0558x over previous
//
#include <hip/hip_runtime.h>

// Problem constants (fixed by reference)
constexpr int N_AG = 4096;   // N agents
constexpr int M_CL = 256;    // M clusters
constexpr int KD   = 32;     // K dim
constexpr float WEPS = 1e-6f;

// ws layout: only vT (32 x 4096) k-major remains.
constexpr int VT_OFF = 0;

typedef __attribute__((ext_vector_type(8))) short short8;   // 8 bf16 (4 VGPRs)
typedef __attribute__((ext_vector_type(4))) float f32x4;

__device__ __forceinline__ float rlane(float x, int l) {
    return __int_as_float(__builtin_amdgcn_readlane(__float_as_int(x), l));
}

__device__ __forceinline__ float fast_rcp(float x) {
#if __has_builtin(__builtin_amdgcn_rcpf)
    float r = __builtin_amdgcn_rcpf(x);      // v_rcp_f32 (~1 ulp)
    return r * (2.0f - x * r);               // +1 NR step -> ~2^-29 rel err
#else
    return 1.0f / x;
#endif
}

// ---------------------------------------------------------------------------
// Solve: row-layout forward elimination + back-substitution (R9).
// Lane r (r = lane&31; lanes 32-63 duplicate rows 0-31 so broadcasts stay
// readlane-uniform, zero divergence) holds row r of A + rhs scalar.
// No pivoting: SPD with diag >= 1. Template-recursive so all a[j] indices
// are compile-time (R6 scratch lesson).
// ---------------------------------------------------------------------------
template<int J>
struct FE {
    static __device__ __forceinline__ void run(float (&a)[32], float& rhs,
                                               float& pl, const int rr) {
        const float piv  = rlane(a[J], J);
        const float pinv = fast_rcp(piv);
        if (rr == J) pl = pinv;                       // save for back-sub
        const float f = (rr > J) ? a[J] * pinv : 0.0f; // rows <= J frozen
        #pragma unroll
        for (int j = J + 1; j < 32; ++j) {
            const float rJ = rlane(a[j], J);
            a[j] = fmaf(-f, rJ, a[j]);
        }
        const float rb = rlane(rhs, J);
        rhs = fmaf(-f, rb, rhs);
        FE<J + 1>::run(a, rhs, pl, rr);
    }
};
template<> struct FE<32> {
    static __device__ __forceinline__ void run(float (&)[32], float&, float&, const int) {}
};

template<int J>
struct BS {
    static __device__ __forceinline__ void run(const float (&a)[32], float& rhs,
                                               const float pl, float& xv, const int rr) {
        const float xj = rlane(rhs, J) * rlane(pl, J);  // uniform
        if (rr == J) xv = xj;
        rhs = fmaf(-a[J], xj, rhs);   // corrupts rr>=J lanes: already consumed
        BS<J - 1>::run(a, rhs, pl, xv, rr);
    }
};
template<> struct BS<-1> {
    static __device__ __forceinline__ void run(const float (&)[32], float&,
                                               const float, float&, const int) {}
};

// ---------------------------------------------------------------------------
// K1: pure solve, 1024 blocks. 4 matrices/block, 1 wave each, then in-block
// LDS transpose -> vT (32 x 4096) k-major.
// ---------------------------------------------------------------------------
__global__ __launch_bounds__(256) void solve_kernel(const float* __restrict__ mu,
                                                    const float* __restrict__ oc,
                                                    float* __restrict__ ws) {
    __shared__ float sv[4][32];
    const int t    = threadIdx.x;
    const int lane = t & 63;
    const int wid  = t >> 6;
    const int n0   = blockIdx.x * 4;
    const int idx  = n0 + wid;
    const int rr   = lane & 31;           // lanes 32-63 mirror rows 0-31

    float a[32];
    const float4* src = reinterpret_cast<const float4*>(oc + (size_t)idx * 1024 + rr * 32);
    #pragma unroll
    for (int q = 0; q < 8; ++q) {
        const float4 t4 = src[q];
        a[4 * q + 0] = t4.x; a[4 * q + 1] = t4.y;
        a[4 * q + 2] = t4.z; a[4 * q + 3] = t4.w;
    }
    float rhs = mu[(size_t)idx * 32 + rr];
    float pl = 0.0f, xv = 0.0f;

    FE<0>::run(a, rhs, pl, rr);
    BS<31>::run(a, rhs, pl, xv, rr);

    if (lane < 32) sv[wid][lane] = xv;
    __syncthreads();
    // vT[k][n0..n0+3]: 16B-coalesced per k-row
    if (t < 128) {
        const int k = t >> 2;
        const int j = t & 3;
        ws[VT_OFF + (size_t)k * 4096 + n0 + j] = sv[j][k];
    }
}

// ---------------------------------------------------------------------------
// K2 (R11 mega-fusion, restored after R12 regression): ONE block per m owns
// all 4096 n. R12's lesson: direct-from-vT fragment loads scatter 16 k-rows
// per load instruction (16x 64B lines/dwordx4 vs 4 coalesced) -> 4x VMEM
// request amplification, +5us. The LDS staging below keeps global loads
// coalesced (consecutive lanes -> consecutive n) and does the lane-layout
// transpose through LDS — that IS its job.
// 256 blocks x 1024 threads (16 waves, 4/SIMD; grid maps 1:1 onto 256 CUs).
// Wave wv owns n in [wv*256, +256), 8 rounds of 32 n; staging buffer
// [2][32k x 20dw]/wave (stride 20 dw = 80 B keeps ds_read_b128 16B-aligned).
// LDS = 81,920 + 16,384 = 98,304 B -> 1 block/CU.
// Math: u = sqrt(w)v hi/lo bf16 split (RTZ), S2 = u^T u via MFMA,
// P = hh + 2*hl (G symmetric => tr(G(hl+hl^T)) = 2 tr(G hl)).
// Epilogue: after the 16-way cross-wave LDS sum, thread t holds EXACTLY
// element t of P in MFMA-lane layout, bijecting to (a,b):
//   q=t>>8, r=(t>>6)&3, a=(q>>1)*16+((t>>4)&3)*4+r, b=(q&1)*16+(t&15)
// so each thread computes G_ab and its psi term locally.
// ---------------------------------------------------------------------------
__global__ __launch_bounds__(1024, 4) void fused_kernel(const float* __restrict__ W,
                                                        const float* __restrict__ vT,
                                                        const float* __restrict__ op,
                                                        float* __restrict__ out) {
    const int m  = blockIdx.x;
    const int t  = threadIdx.x;
    const int lane = t & 63;
    const int wv   = t >> 6;     // wave id 0..15

    __shared__ unsigned ubuf[16][2][640];  // [wave][hi/lo][k*20 + n/2] : 81,920 B
    __shared__ float swbuf[4096];          // sqrt(w); dead after main loop: 16,384 B
    // post-loop overlays inside swbuf:
    float* const s1buf = swbuf;            // [0..31]
    float* const zredL = swbuf + 32;       // [32..47]
    float* const credL = swbuf + 48;       // [48..63]
    float* const omg   = swbuf + 64;       // [64..1119]  32*33
    float* const vbar  = swbuf + 1120;     // [1120..1151]
    float* const red2  = swbuf + 1152;     // [1152..1167]

    // ---- stage w: direct strided W read (column m), mask, sqrt, Z, count ----
    // thread t covers rows 4t..4t+3; wave wv's conversion reads swbuf slice
    // [wv*256, +256) written by its own threads -> wave-private, no barrier.
    const int rbase = t * 4;
    const float w0 = W[(size_t)(rbase + 0) * 256 + m];
    const float w1 = W[(size_t)(rbase + 1) * 256 + m];
    const float w2 = W[(size_t)(rbase + 2) * 256 + m];
    const float w3 = W[(size_t)(rbase + 3) * 256 + m];
    const float m0 = (w0 >= WEPS) ? w0 : 0.0f;
    const float m1 = (w1 >= WEPS) ? w1 : 0.0f;
    const float m2 = (w2 >= WEPS) ? w2 : 0.0f;
    const float m3 = (w3 >= WEPS) ? w3 : 0.0f;
    float zacc = m0 + m1 + m2 + m3;
    float cacc = (w0 >= WEPS ? 1.f : 0.f) + (w1 >= WEPS ? 1.f : 0.f)
               + (w2 >= WEPS ? 1.f : 0.f) + (w3 >= WEPS ? 1.f : 0.f);
    reinterpret_cast<float4*>(swbuf)[t] =
        make_float4(sqrtf(m0), sqrtf(m1), sqrtf(m2), sqrtf(m3));

    f32x4 Chh[4], Chl[4];
    #pragma unroll
    for (int q = 0; q < 4; ++q) {
        Chh[q] = (f32x4){0.f, 0.f, 0.f, 0.f};
        Chl[q] = (f32x4){0.f, 0.f, 0.f, 0.f};
    }
    float s1acc[4] = {0.f, 0.f, 0.f, 0.f};

    const int krow = lane >> 3;        // 0..7
    const int nsub = (lane & 7) * 4;   // 0..28

    for (int rnd = 0; rnd < 8; ++rnd) {
        const int nloc0 = wv * 256 + rnd * 32;   // global n base of this wave-round

        // ---- conversion: 32 n x 32 k, fp32 -> u -> bf16 hi/lo in LDS ----
        #pragma unroll
        for (int it = 0; it < 4; ++it) {
            const int k = krow + 8 * it;
            const float4 v4 = *reinterpret_cast<const float4*>(
                vT + (size_t)k * 4096 + nloc0 + nsub);
            const float4 s4 = *reinterpret_cast<const float4*>(&swbuf[nloc0 + nsub]);
            const float ux = v4.x * s4.x, uy = v4.y * s4.y;
            const float uz = v4.z * s4.z, uw = v4.w * s4.w;
            const unsigned bx = __float_as_uint(ux), by = __float_as_uint(uy);
            const unsigned bz = __float_as_uint(uz), bw = __float_as_uint(uw);
            const unsigned hi01 = __builtin_amdgcn_perm(by, bx, 0x07060302u);
            const unsigned hi23 = __builtin_amdgcn_perm(bw, bz, 0x07060302u);
            const float lx = ux - __uint_as_float(bx & 0xFFFF0000u);
            const float ly = uy - __uint_as_float(by & 0xFFFF0000u);
            const float lz = uz - __uint_as_float(bz & 0xFFFF0000u);
            const float lw = uw - __uint_as_float(bw & 0xFFFF0000u);
            const unsigned lo01 = __builtin_amdgcn_perm(__float_as_uint(ly), __float_as_uint(lx), 0x07060302u);
            const unsigned lo23 = __builtin_amdgcn_perm(__float_as_uint(lw), __float_as_uint(lz), 0x07060302u);
            const int dwi = k * 20 + (nsub >> 1);
            *reinterpret_cast<uint2*>(&ubuf[wv][0][dwi]) = make_uint2(hi01, hi23);
            *reinterpret_cast<uint2*>(&ubuf[wv][1][dwi]) = make_uint2(lo01, lo23);
            // S1 += w*v = sw*u
            s1acc[it] += ux * s4.x + uy * s4.y + uz * s4.z + uw * s4.w;
        }

        // ---- MFMA: one 32-n chunk ----
        const int r0 = (lane & 15) * 20 + ((lane >> 4) << 2);
        const int r1 = r0 + 320;
        const short8 h0 = *reinterpret_cast<const short8*>(&ubuf[wv][0][r0]);
        const short8 h1 = *reinterpret_cast<const short8*>(&ubuf[wv][0][r1]);
        const short8 l0 = *reinterpret_cast<const short8*>(&ubuf[wv][1][r0]);
        const short8 l1 = *reinterpret_cast<const short8*>(&ubuf[wv][1][r1]);
        Chh[0] = __builtin_amdgcn_mfma_f32_16x16x32_bf16(h0, h0, Chh[0], 0, 0, 0);
        Chh[1] = __builtin_amdgcn_mfma_f32_16x16x32_bf16(h0, h1, Chh[1], 0, 0, 0);
        Chh[2] = __builtin_amdgcn_mfma_f32_16x16x32_bf16(h1, h0, Chh[2], 0, 0, 0);
        Chh[3] = __builtin_amdgcn_mfma_f32_16x16x32_bf16(h1, h1, Chh[3], 0, 0, 0);
        Chl[0] = __builtin_amdgcn_mfma_f32_16x16x32_bf16(h0, l0, Chl[0], 0, 0, 0);
        Chl[1] = __builtin_amdgcn_mfma_f32_16x16x32_bf16(h0, l1, Chl[1], 0, 0, 0);
        Chl[2] = __builtin_amdgcn_mfma_f32_16x16x32_bf16(h1, l0, Chl[2], 0, 0, 0);
        Chl[3] = __builtin_amdgcn_mfma_f32_16x16x32_bf16(h1, l1, Chl[3], 0, 0, 0);
    }

    // ---- P scatter: P = hh + 2*hl in MFMA-native lane layout (wave-private) ----
    float* redw = reinterpret_cast<float*>(&ubuf[wv][0][0]);  // 1024 of 1280 dw
    #pragma unroll
    for (int q = 0; q < 4; ++q) {
        #pragma unroll
        for (int r = 0; r < 4; ++r) {
            redw[q * 256 + r * 64 + lane] = Chh[q][r] + 2.0f * Chl[q][r];
        }
    }

    // ---- wave-level Z/count reduce (registers) ----
    #pragma unroll
    for (int s = 1; s < 64; s <<= 1) {
        zacc += __shfl_xor(zacc, s);
        cacc += __shfl_xor(cacc, s);
    }

    __syncthreads();   // B1: all scatters done; swbuf dead -> overlays live

    if (t < 32) s1buf[t] = 0.0f;
    if (lane == 0) { zredL[wv] = zacc; credL[wv] = cacc; }
    omg[(t >> 5) * 33 + (t & 31)] = op[(size_t)m * 1024 + t];

    // ---- cross-wave P sum: thread t accumulates element t over 16 waves ----
    float Ptot = 0.0f;
    const float* ub = reinterpret_cast<const float*>(&ubuf[0][0][0]);
    #pragma unroll
    for (int ww = 0; ww < 16; ++ww) Ptot += ub[ww * 1280 + t];

    __syncthreads();   // B2: s1buf zeroed, omg/zred/cred staged

    // ---- S1 reduce: 8 consecutive lanes share k ----
    #pragma unroll
    for (int j = 0; j < 4; ++j) {
        float r = s1acc[j];
        r += __shfl_xor(r, 1);
        r += __shfl_xor(r, 2);
        r += __shfl_xor(r, 4);
        if ((lane & 7) == 0) atomicAdd(&s1buf[krow + 8 * j], r);
    }
    __syncthreads();   // B3: s1 complete

    float Z = 0.0f, C = 0.0f;
    #pragma unroll
    for (int w = 0; w < 16; ++w) { Z += zredL[w]; C += credL[w]; }
    const float invZ = 1.0f / fmaxf(Z, 1e-30f);
    if (t < 32) vbar[t] = s1buf[t] * invZ;
    __syncthreads();   // B4: vbar ready

    // ---- per-thread combine: (a,b) from the P lane-layout bijection ----
    const int q = t >> 8;
    const int r = (t >> 6) & 3;
    const int a = (q >> 1) * 16 + ((t >> 4) & 3) * 4 + r;
    const int b = (q & 1) * 16 + (t & 15);
    float G = 0.0f;
    #pragma unroll
    for (int i = 0; i < 32; ++i)
        G = fmaf(omg[i * 33 + a], omg[i * 33 + b], G);
    float val = G * (Ptot * invZ - vbar[a] * vbar[b]);

    #pragma unroll
    for (int s = 1; s < 64; s <<= 1) val += __shfl_xor(val, s);
    if (lane == 0) red2[wv] = val;
    __syncthreads();   // B5
    if (t == 0) {
        float acc = 0.0f;
        #pragma unroll
        for (int w = 0; w < 16; ++w) acc += red2[w];
        out[m] = (C >= 1.5f) ? acc : 0.0f;
    }
}

// ---------------------------------------------------------------------------
extern "C" void kernel_launch(void* const* d_in, const int* in_sizes, int n_in,
                              void* d_out, int out_size, void* d_ws, size_t ws_size,
                              hipStream_t stream) {
    const float* W  = (const float*)d_in[0];  // (4096, 256)
    const float* mu = (const float*)d_in[1];  // (4096, 32)
    const float* oc = (const float*)d_in[2];  // (4096, 32, 32)
    const float* op = (const float*)d_in[3];  // (256, 32, 32)
    float* out = (float*)d_out;               // (256,)
    float* ws  = (float*)d_ws;

    solve_kernel<<<1024, 256, 0, stream>>>(mu, oc, ws);
    fused_kernel<<<256, 1024, 0, stream>>>(W, ws + VT_OFF, op, out);
}